// Round 4
// baseline (10292.657 us; speedup 1.0000x reference)
//
#include <hip/hip_runtime.h>
#include <math.h>

#define D 64

__device__ __forceinline__ float bf2f(unsigned short u) {
    union { unsigned int i; float f; } v; v.i = ((unsigned int)u) << 16; return v.f;
}
__device__ __forceinline__ unsigned short f2bf(float f) {
    union { float f; unsigned int i; } v; v.f = f;
    unsigned int r = v.i + 0x7FFFu + ((v.i >> 16) & 1u);
    return (unsigned short)(r >> 16);
}

// ============================ initial gather (both tables, one launch) ============================
__global__ __launch_bounds__(256) void k_gather2(const float* __restrict__ ue,
                                                 const float* __restrict__ ie,
                                                 const int* __restrict__ uid,
                                                 const int* __restrict__ iid,
                                                 float* __restrict__ uh0,
                                                 float* __restrict__ ih0, int NU, int NI) {
    int i = blockIdx.x * blockDim.x + threadIdx.x;
    if (i >= (NU + NI) * D) return;
    int r = i >> 6, c = i & 63;
    if (r < NU) uh0[(size_t)r * D + c] = ue[(size_t)uid[r] * D + c];
    else { int j = r - NU; ih0[(size_t)j * D + c] = ie[(size_t)iid[j] * D + c]; }
}

// ============================ CSR build (both relations per launch) ============================
__global__ __launch_bounds__(256) void k_hist2(const int* __restrict__ bd,
                                               const int* __restrict__ pd,
                                               int* __restrict__ cu, int* __restrict__ ci, int E) {
    for (int i = blockIdx.x * blockDim.x + threadIdx.x; i < 2 * E; i += gridDim.x * blockDim.x) {
        if (i < E) atomicAdd(&cu[bd[i]], 1);
        else       atomicAdd(&ci[pd[i - E]], 1);
    }
}

__global__ __launch_bounds__(256) void k_scan_block2(const int* __restrict__ cu, int* __restrict__ rp_u,
                                                     const int* __restrict__ ci, int* __restrict__ rp_i,
                                                     int* __restrict__ bsums, int nbU, int NU, int NI) {
    __shared__ int ts[256];
    bool rel = blockIdx.x >= (unsigned)nbU;
    const int* in = rel ? ci : cu;
    int* out = rel ? rp_i : rp_u;
    int n = rel ? NI : NU;
    int boff = rel ? blockIdx.x - nbU : blockIdx.x;
    int t = threadIdx.x;
    int base = boff * 2048 + t * 8;
    int v[8]; int s = 0;
#pragma unroll
    for (int k = 0; k < 8; ++k) { int idx = base + k; v[k] = idx < n ? in[idx] : 0; s += v[k]; }
    ts[t] = s; __syncthreads();
    for (int off = 1; off < 256; off <<= 1) {
        int x = (t >= off) ? ts[t - off] : 0;
        __syncthreads(); ts[t] += x; __syncthreads();
    }
    int excl = ts[t] - s;
    if (t == 255) bsums[blockIdx.x] = ts[255];
    int run = excl;
#pragma unroll
    for (int k = 0; k < 8; ++k) { int idx = base + k; if (idx < n) out[idx] = run; run += v[k]; }
}

// in-place exclusive scan of bsums, two segments [0,nbU) and [nbU,nbU+nbI), each <=128
__global__ __launch_bounds__(256) void k_scan_small(int* __restrict__ bsums, int nbU, int nbI) {
    __shared__ int ts[256];
    int t = threadIdx.x;
    int half = t >> 7, local = t & 127;
    int nb = half ? nbI : nbU;
    int g = half ? nbU + local : local;
    int v = local < nb ? bsums[g] : 0;
    ts[t] = v; __syncthreads();
    for (int off = 1; off < 128; off <<= 1) {
        int x = (local >= off) ? ts[t - off] : 0;
        __syncthreads(); ts[t] += x; __syncthreads();
    }
    if (local < nb) bsums[g] = ts[t] - v;
}

__global__ __launch_bounds__(256) void k_fixup2(int* __restrict__ rp_u, int* __restrict__ rp_i,
                                                const int* __restrict__ bsums,
                                                int* __restrict__ cu, int* __restrict__ ci,
                                                int NU, int NI, int E, int nbU) {
    int i = blockIdx.x * blockDim.x + threadIdx.x;
    if (i < NU) {
        int v = rp_u[i] + bsums[i >> 11]; rp_u[i] = v; cu[i] = v;
        if (i == 0) rp_u[NU] = E;
    } else if (i < NU + NI) {
        int j = i - NU;
        int v = rp_i[j] + bsums[nbU + (j >> 11)]; rp_i[j] = v; ci[j] = v;
        if (j == 0) rp_i[NI] = E;
    }
}

__global__ __launch_bounds__(256) void k_scatter2(
    const int* __restrict__ bs, const int* __restrict__ bd, const float* __restrict__ bt,
    const int* __restrict__ ps, const int* __restrict__ pd, const float* __restrict__ pt,
    int* __restrict__ cu, int* __restrict__ ci,
    int* __restrict__ bso, float* __restrict__ bto, int* __restrict__ bdo_,
    int* __restrict__ pso, float* __restrict__ pto, int* __restrict__ pdo_, int E) {
    for (int i = blockIdx.x * blockDim.x + threadIdx.x; i < 2 * E; i += gridDim.x * blockDim.x) {
        if (i < E) {
            int d = bd[i]; int pos = atomicAdd(&cu[d], 1);
            bso[pos] = bs[i]; bto[pos] = bt[i]; bdo_[pos] = d;
        } else {
            int k = i - E;
            int d = pd[k]; int pos = atomicAdd(&ci[d], 1);
            pso[pos] = ps[k]; pto[pos] = pt[k]; pdo_[pos] = d;
        }
    }
}

// ============================ transform (both tables, 32 rows/block) ============================
__global__ __launch_bounds__(256) void k_transform2(
    const float* __restrict__ user_h, const float* __restrict__ item_h,
    const float* __restrict__ Wu_l, const float* __restrict__ Wi_l,
    unsigned short* __restrict__ uh, unsigned short* __restrict__ ih,
    int NU, int NI, int UB) {
    bool rel = blockIdx.x >= (unsigned)UB;
    int b = rel ? blockIdx.x - UB : blockIdx.x;
    const float* in = rel ? item_h : user_h;
    const float* W  = rel ? Wi_l : Wu_l;
    unsigned short* out = rel ? ih : uh;
    int n = rel ? NI : NU;
    __shared__ float Ws[D * D];
    int t = threadIdx.x;
#pragma unroll
    for (int i = 0; i < 16; ++i) Ws[i * 256 + t] = W[i * 256 + t];
    __syncthreads();
    int lane = t & 63, wid = t >> 6;
    int rbase = b * 32 + wid * 8;
    float iv[8], o[8];
#pragma unroll
    for (int r = 0; r < 8; ++r) {
        int row = rbase + r;
        iv[r] = row < n ? in[(size_t)row * D + lane] : 0.f;
        o[r] = 0.f;
    }
#pragma unroll
    for (int d = 0; d < D; ++d) {
        float w = Ws[d * D + lane];
#pragma unroll
        for (int r = 0; r < 8; ++r) o[r] = fmaf(__shfl(iv[r], d), w, o[r]);
    }
#pragma unroll
    for (int r = 0; r < 8; ++r) {
        int row = rbase + r;
        if (row < n) out[(size_t)row * D + lane] = f2bf(o[r]);
    }
}

// ============================ edge kernel: 16-lane groups, 4 edges/wave ============================
// group of 16 lanes handles one edge at a time, lane covers dims [lane*4, lane*4+4)
__global__ __launch_bounds__(256) void k_edge2(
    const unsigned short* __restrict__ ihF, const unsigned short* __restrict__ uhF,
    const int* __restrict__ by_s, const int* __restrict__ by_d, const float* __restrict__ by_t,
    const int* __restrict__ pby_s, const int* __restrict__ pby_d, const float* __restrict__ pby_t,
    const float* __restrict__ uf, const float* __restrict__ up,
    const float* __restrict__ ukf, const float* __restrict__ ukp,
    const float* __restrict__ ifq, const float* __restrict__ ipq,
    const float* __restrict__ ikf, const float* __restrict__ ikp,
    float* __restrict__ agg_u, float* __restrict__ den_u,
    float* __restrict__ agg_i, float* __restrict__ den_i,
    int E, int EB) {
    bool rel = blockIdx.x >= (unsigned)EB;  // false: 'by' item->user, true: 'pby' user->item
    int rblk = rel ? blockIdx.x - EB : blockIdx.x;
    const unsigned short* srcF = rel ? uhF : ihF;
    const unsigned short* dstF = rel ? ihF : uhF;
    const int* es = rel ? pby_s : by_s;
    const int* ed = rel ? pby_d : by_d;
    const float* et = rel ? pby_t : by_t;
    const float* efq = rel ? ifq : uf;
    const float* eps = rel ? ipq : up;
    const float* kfq = rel ? ikf : ukf;
    const float* kps = rel ? ikp : ukp;
    float* agg = rel ? agg_i : agg_u;
    float* den = rel ? den_i : den_u;

    int lane = threadIdx.x & 15;
    int grp  = threadIdx.x >> 4;
    int base = rblk * 256 + grp * 16;
    if (base >= E) return;
    float4 ef4 = ((const float4*)efq)[lane];
    float4 ep4 = ((const float4*)eps)[lane];
    float4 kf4 = ((const float4*)kfq)[lane];
    float4 kp4 = ((const float4*)kps)[lane];
    bool same = ef4.x == kf4.x && ef4.y == kf4.y && ef4.z == kf4.z && ef4.w == kf4.w &&
                ep4.x == kp4.x && ep4.y == kp4.y && ep4.z == kp4.z && ep4.w == kp4.w;
    same = __all(same);  // uniform: key time-encode identical to e time-encode

    float a0 = 0, a1 = 0, a2 = 0, a3 = 0, dn = 0;
    float d0 = 0, d1 = 0, d2 = 0, d3 = 0;
    int cur = -1;
    for (int j = 0; j < 16; ++j) {
        int e = base + j;
        if (e >= E) break;
        int s = es[e]; int dd = ed[e]; float t = et[e];
        if (dd != cur) {  // group-uniform
            if (cur >= 0) {
                float* ap = &agg[(size_t)cur * D + lane * 4];
                unsafeAtomicAdd(ap + 0, a0); unsafeAtomicAdd(ap + 1, a1);
                unsafeAtomicAdd(ap + 2, a2); unsafeAtomicAdd(ap + 3, a3);
                if (lane == 0) unsafeAtomicAdd(&den[cur], dn);
            }
            a0 = a1 = a2 = a3 = 0; dn = 0; cur = dd;
            ushort4 dq = *(const ushort4*)&dstF[(size_t)dd * D + lane * 4];
            d0 = bf2f(dq.x); d1 = bf2f(dq.y); d2 = bf2f(dq.z); d3 = bf2f(dq.w);
        }
        ushort4 sq = *(const ushort4*)&srcF[(size_t)s * D + lane * 4];
        float s0 = bf2f(sq.x), s1 = bf2f(sq.y), s2 = bf2f(sq.z), s3 = bf2f(sq.w);
        float c0 = __cosf(fmaf(t, ef4.x, ep4.x));
        float c1 = __cosf(fmaf(t, ef4.y, ep4.y));
        float c2 = __cosf(fmaf(t, ef4.z, ep4.z));
        float c3 = __cosf(fmaf(t, ef4.w, ep4.w));
        float p = (c0 + s0) * d0 + (c1 + s1) * d1 + (c2 + s2) * d2 + (c3 + s3) * d3;
        p += __shfl_xor(p, 1); p += __shfl_xor(p, 2);
        p += __shfl_xor(p, 4); p += __shfl_xor(p, 8);
        float ex = __expf(p * 0.125f);
        float k0, k1, k2, k3;
        if (same) { k0 = c0; k1 = c1; k2 = c2; k3 = c3; }
        else {
            k0 = __cosf(fmaf(t, kf4.x, kp4.x)); k1 = __cosf(fmaf(t, kf4.y, kp4.y));
            k2 = __cosf(fmaf(t, kf4.z, kp4.z)); k3 = __cosf(fmaf(t, kf4.w, kp4.w));
        }
        a0 = fmaf(ex, s0 + k0, a0); a1 = fmaf(ex, s1 + k1, a1);
        a2 = fmaf(ex, s2 + k2, a2); a3 = fmaf(ex, s3 + k3, a3);
        dn += ex;
    }
    if (cur >= 0) {
        float* ap = &agg[(size_t)cur * D + lane * 4];
        unsafeAtomicAdd(ap + 0, a0); unsafeAtomicAdd(ap + 1, a1);
        unsafeAtomicAdd(ap + 2, a2); unsafeAtomicAdd(ap + 3, a3);
        if (lane == 0) unsafeAtomicAdd(&den[cur], dn);
    }
}

// ============================ update (both tables, 16 rows/block) ============================
__global__ __launch_bounds__(256) void k_update2(
    float* __restrict__ user_h, float* __restrict__ item_h,
    const float* __restrict__ agg_u, const float* __restrict__ den_u,
    const float* __restrict__ agg_i, const float* __restrict__ den_i,
    const float* __restrict__ Wuu_l, const float* __restrict__ Wii_l,
    int NU, int NI, int UB) {
    bool rel = blockIdx.x >= (unsigned)UB;
    int b = rel ? blockIdx.x - UB : blockIdx.x;
    float* h = rel ? item_h : user_h;
    const float* agg = rel ? agg_i : agg_u;
    const float* den = rel ? den_i : den_u;
    const float* W2  = rel ? Wii_l : Wuu_l;
    int n = rel ? NI : NU;
    __shared__ float Ws[2 * D * D];  // 32 KB
    int t = threadIdx.x;
#pragma unroll
    for (int i = 0; i < 32; ++i) Ws[i * 256 + t] = W2[i * 256 + t];
    __syncthreads();
    int lane = t & 63, wid = t >> 6;
    int rbase = b * 16 + wid * 4;
    float aN[4], hN[4], o[4];
#pragma unroll
    for (int r = 0; r < 4; ++r) {
        int row = rbase + r;
        if (row < n) {
            float dd = den[row];
            float inv = dd > 0.f ? 1.f / dd : 0.f;  // empty segment -> zeros
            aN[r] = agg[(size_t)row * D + lane] * inv;
            hN[r] = h[(size_t)row * D + lane];
        } else { aN[r] = 0.f; hN[r] = 0.f; }
        o[r] = 0.f;
    }
#pragma unroll
    for (int d = 0; d < D; ++d) {
        float w = Ws[d * D + lane];
#pragma unroll
        for (int r = 0; r < 4; ++r) o[r] = fmaf(__shfl(aN[r], d), w, o[r]);
    }
#pragma unroll
    for (int d = 0; d < D; ++d) {
        float w = Ws[(D + d) * D + lane];
#pragma unroll
        for (int r = 0; r < 4; ++r) o[r] = fmaf(__shfl(hN[r], d), w, o[r]);
    }
#pragma unroll
    for (int r = 0; r < 4; ++r) {
        int row = rbase + r;
        if (row < n) h[(size_t)row * D + lane] = o[r] > 0.f ? o[r] : __expf(o[r]) - 1.f;
    }
}

// ============================ tail ============================
__global__ __launch_bounds__(256) void k_gather_feat(const float* __restrict__ h,
                                                     const int* __restrict__ idx,
                                                     float* __restrict__ feat, int B,
                                                     int colOff, int FW) {
    int i = blockIdx.x * blockDim.x + threadIdx.x;
    if (i >= B * D) return;
    int b = i >> 6, c = i & 63;
    feat[(size_t)b * FW + colOff + c] = h[(size_t)idx[b] * D + c];
}

__global__ __launch_bounds__(64) void k_final(const float* __restrict__ feat,
                                              const float* __restrict__ uW,
                                              const float* __restrict__ dW,
                                              const float* __restrict__ db,
                                              float* __restrict__ out, int B, int FW) {
    __shared__ float fr[512];
    __shared__ float un[D];
    int b = blockIdx.x;
    int c = threadIdx.x;
    for (int i = c; i < FW; i += 64) fr[i] = feat[(size_t)b * FW + i];
    __syncthreads();
    float acc = 0.f;
    for (int d = 0; d < FW; ++d) acc += fr[d] * uW[d * D + c];
    un[c] = acc;
    __syncthreads();
    if (c < 3) {
        float o = db[c];
#pragma unroll
        for (int d = 0; d < D; ++d) o += un[d] * dW[d * 3 + c];
        out[b * 3 + c] = o > 0.f ? o : 0.f;
    }
}

// ============================ launch ============================
extern "C" void kernel_launch(void* const* d_in, const int* in_sizes, int n_in,
                              void* d_out, int out_size, void* d_ws, size_t ws_size,
                              hipStream_t stream) {
    const float* user_emb = (const float*)d_in[0];
    const float* item_emb = (const float*)d_in[1];
    const float* Wu       = (const float*)d_in[2];
    const float* Wi       = (const float*)d_in[3];
    const float* Wuu      = (const float*)d_in[4];
    const float* Wii      = (const float*)d_in[5];
    const float* u_freq   = (const float*)d_in[6];
    const float* u_phase  = (const float*)d_in[7];
    const float* uk_freq  = (const float*)d_in[8];
    const float* uk_phase = (const float*)d_in[9];
    const float* i_freq   = (const float*)d_in[10];
    const float* i_phase  = (const float*)d_in[11];
    const float* ik_freq  = (const float*)d_in[12];
    const float* ik_phase = (const float*)d_in[13];
    const float* unified_W = (const float*)d_in[14];
    const float* dense_W   = (const float*)d_in[15];
    const float* dense_b   = (const float*)d_in[16];
    const float* by_time   = (const float*)d_in[17];
    const float* pby_time  = (const float*)d_in[18];
    const int* user_id   = (const int*)d_in[19];
    const int* item_id   = (const int*)d_in[20];
    const int* by_src    = (const int*)d_in[21];
    const int* by_dst    = (const int*)d_in[22];
    const int* pby_src   = (const int*)d_in[23];
    const int* pby_dst   = (const int*)d_in[24];
    const int* user_index = (const int*)d_in[25];
    const int* last_item_index = (const int*)d_in[26];

    const int NU = in_sizes[19];
    const int NI = in_sizes[20];
    const int E  = in_sizes[21];
    const int B  = in_sizes[25];
    const int L  = in_sizes[2] / (D * D);
    const int FW = (L + 1) * D;

    // ---- workspace: [agg_u|agg_i|den_u|den_i] zeroed per layer; [cur_u|cur_i] zeroed once ----
    char* wp = (char*)d_ws;
    auto alloc_f = [&](size_t n) { float* p = (float*)wp; wp += n * sizeof(float); return p; };
    auto alloc_i = [&](size_t n) { int* p = (int*)wp; wp += n * sizeof(int); return p; };
    auto alloc_h = [&](size_t n) { unsigned short* p = (unsigned short*)wp; wp += n * sizeof(unsigned short); return p; };
    float* agg_u = alloc_f((size_t)NU * D);
    float* agg_i = alloc_f((size_t)NI * D);
    float* den_u = alloc_f(NU);
    float* den_i = alloc_f(NI);
    size_t zero_bytes = (size_t)(wp - (char*)d_ws);
    int* cur_u = alloc_i(NU);
    int* cur_i = alloc_i(NI);
    size_t cur_bytes = (size_t)NU * 4 + (size_t)NI * 4;
    float* user_h = alloc_f((size_t)NU * D);
    float* item_h = alloc_f((size_t)NI * D);
    unsigned short* uh = alloc_h((size_t)NU * D);
    unsigned short* ih = alloc_h((size_t)NI * D);
    int*   by_rowptr  = alloc_i(NU + 1);
    int*   by_srcs    = alloc_i(E);
    float* by_times   = alloc_f(E);
    int*   by_dsts    = alloc_i(E);
    int*   pby_rowptr = alloc_i(NI + 1);
    int*   pby_srcs   = alloc_i(E);
    float* pby_times  = alloc_f(E);
    int*   pby_dsts   = alloc_i(E);
    int*   bsums      = alloc_i(512);
    float* feat       = alloc_f((size_t)B * FW);

    const int nbU = (NU + 2047) / 2048, nbI = (NI + 2047) / 2048;

    // initial node features
    k_gather2<<<((NU + NI) * D + 255) / 256, 256, 0, stream>>>(
        user_emb, item_emb, user_id, item_id, user_h, item_h, NU, NI);

    // dst-sorted edge lists, both relations
    hipMemsetAsync(cur_u, 0, cur_bytes, stream);
    k_hist2<<<2048, 256, 0, stream>>>(by_dst, pby_dst, cur_u, cur_i, E);
    k_scan_block2<<<nbU + nbI, 256, 0, stream>>>(cur_u, by_rowptr, cur_i, pby_rowptr,
                                                 bsums, nbU, NU, NI);
    k_scan_small<<<1, 256, 0, stream>>>(bsums, nbU, nbI);
    k_fixup2<<<(NU + NI + 255) / 256, 256, 0, stream>>>(by_rowptr, pby_rowptr, bsums,
                                                        cur_u, cur_i, NU, NI, E, nbU);
    k_scatter2<<<2048, 256, 0, stream>>>(by_src, by_dst, by_time,
                                         pby_src, pby_dst, pby_time,
                                         cur_u, cur_i,
                                         by_srcs, by_times, by_dsts,
                                         pby_srcs, pby_times, pby_dsts, E);

    const int EB = (E + 255) / 256;
    const int TB = (NU + 31) / 32, TBI = (NI + 31) / 32;
    const int UB = (NU + 15) / 16, UBI = (NI + 15) / 16;
    for (int l = 0; l < L; ++l) {
        hipMemsetAsync(d_ws, 0, zero_bytes, stream);
        k_transform2<<<TB + TBI, 256, 0, stream>>>(user_h, item_h,
                                                   Wu + l * D * D, Wi + l * D * D,
                                                   uh, ih, NU, NI, TB);
        k_edge2<<<2 * EB, 256, 0, stream>>>(
            ih, uh,
            by_srcs, by_dsts, by_times,
            pby_srcs, pby_dsts, pby_times,
            u_freq + l * D, u_phase + l * D, uk_freq + l * D, uk_phase + l * D,
            i_freq + l * D, i_phase + l * D, ik_freq + l * D, ik_phase + l * D,
            agg_u, den_u, agg_i, den_i, E, EB);
        k_update2<<<UB + UBI, 256, 0, stream>>>(user_h, item_h,
                                                agg_u, den_u, agg_i, den_i,
                                                Wuu + (size_t)l * 2 * D * D,
                                                Wii + (size_t)l * 2 * D * D,
                                                NU, NI, UB);
        k_gather_feat<<<(B * D + 255) / 256, 256, 0, stream>>>(user_h, user_index, feat, B,
                                                               l * D, FW);
    }
    k_gather_feat<<<(B * D + 255) / 256, 256, 0, stream>>>(item_h, last_item_index, feat, B,
                                                           L * D, FW);
    k_final<<<B, 64, 0, stream>>>(feat, unified_W, dense_W, dense_b, (float*)d_out, B, FW);
}

// Round 5
// 2141.350 us; speedup vs baseline: 4.8066x; 4.8066x over previous
//
#include <hip/hip_runtime.h>
#include <math.h>

#define D 64

__device__ __forceinline__ float bf2f(unsigned short u) {
    union { unsigned int i; float f; } v; v.i = ((unsigned int)u) << 16; return v.f;
}
__device__ __forceinline__ unsigned short f2bf(float f) {
    union { float f; unsigned int i; } v; v.f = f;
    unsigned int r = v.i + 0x7FFFu + ((v.i >> 16) & 1u);
    return (unsigned short)(r >> 16);
}

// ============================ initial gather (both tables, one launch) ============================
__global__ __launch_bounds__(256) void k_gather2(const float* __restrict__ ue,
                                                 const float* __restrict__ ie,
                                                 const int* __restrict__ uid,
                                                 const int* __restrict__ iid,
                                                 float* __restrict__ uh0,
                                                 float* __restrict__ ih0, int NU, int NI) {
    int i = blockIdx.x * blockDim.x + threadIdx.x;
    if (i >= (NU + NI) * D) return;
    int r = i >> 6, c = i & 63;
    if (r < NU) uh0[(size_t)r * D + c] = ue[(size_t)uid[r] * D + c];
    else { int j = r - NU; ih0[(size_t)j * D + c] = ie[(size_t)iid[j] * D + c]; }
}

// ============================ CSR build (both relations per launch) ============================
__global__ __launch_bounds__(256) void k_hist2(const int* __restrict__ bd,
                                               const int* __restrict__ pd,
                                               int* __restrict__ cu, int* __restrict__ ci, int E) {
    for (int i = blockIdx.x * blockDim.x + threadIdx.x; i < 2 * E; i += gridDim.x * blockDim.x) {
        if (i < E) atomicAdd(&cu[bd[i]], 1);
        else       atomicAdd(&ci[pd[i - E]], 1);
    }
}

__global__ __launch_bounds__(256) void k_scan_block2(const int* __restrict__ cu, int* __restrict__ rp_u,
                                                     const int* __restrict__ ci, int* __restrict__ rp_i,
                                                     int* __restrict__ bsums, int nbU, int NU, int NI) {
    __shared__ int ts[256];
    bool rel = blockIdx.x >= (unsigned)nbU;
    const int* in = rel ? ci : cu;
    int* out = rel ? rp_i : rp_u;
    int n = rel ? NI : NU;
    int boff = rel ? blockIdx.x - nbU : blockIdx.x;
    int t = threadIdx.x;
    int base = boff * 2048 + t * 8;
    int v[8]; int s = 0;
#pragma unroll
    for (int k = 0; k < 8; ++k) { int idx = base + k; v[k] = idx < n ? in[idx] : 0; s += v[k]; }
    ts[t] = s; __syncthreads();
    for (int off = 1; off < 256; off <<= 1) {
        int x = (t >= off) ? ts[t - off] : 0;
        __syncthreads(); ts[t] += x; __syncthreads();
    }
    int excl = ts[t] - s;
    if (t == 255) bsums[blockIdx.x] = ts[255];
    int run = excl;
#pragma unroll
    for (int k = 0; k < 8; ++k) { int idx = base + k; if (idx < n) out[idx] = run; run += v[k]; }
}

// in-place exclusive scan of bsums, two segments [0,nbU) and [nbU,nbU+nbI), each <=128
__global__ __launch_bounds__(256) void k_scan_small(int* __restrict__ bsums, int nbU, int nbI) {
    __shared__ int ts[256];
    int t = threadIdx.x;
    int half = t >> 7, local = t & 127;
    int nb = half ? nbI : nbU;
    int g = half ? nbU + local : local;
    int v = local < nb ? bsums[g] : 0;
    ts[t] = v; __syncthreads();
    for (int off = 1; off < 128; off <<= 1) {
        int x = (local >= off) ? ts[t - off] : 0;
        __syncthreads(); ts[t] += x; __syncthreads();
    }
    if (local < nb) bsums[g] = ts[t] - v;
}

__global__ __launch_bounds__(256) void k_fixup2(int* __restrict__ rp_u, int* __restrict__ rp_i,
                                                const int* __restrict__ bsums,
                                                int* __restrict__ cu, int* __restrict__ ci,
                                                int NU, int NI, int E, int nbU) {
    int i = blockIdx.x * blockDim.x + threadIdx.x;
    if (i < NU) {
        int v = rp_u[i] + bsums[i >> 11]; rp_u[i] = v; cu[i] = v;
        if (i == 0) rp_u[NU] = E;
    } else if (i < NU + NI) {
        int j = i - NU;
        int v = rp_i[j] + bsums[nbU + (j >> 11)]; rp_i[j] = v; ci[j] = v;
        if (j == 0) rp_i[NI] = E;
    }
}

__global__ __launch_bounds__(256) void k_scatter2(
    const int* __restrict__ bs, const int* __restrict__ bd, const float* __restrict__ bt,
    const int* __restrict__ ps, const int* __restrict__ pd, const float* __restrict__ pt,
    int* __restrict__ cu, int* __restrict__ ci,
    int* __restrict__ bso, float* __restrict__ bto, int* __restrict__ bdo_,
    int* __restrict__ pso, float* __restrict__ pto, int* __restrict__ pdo_, int E) {
    for (int i = blockIdx.x * blockDim.x + threadIdx.x; i < 2 * E; i += gridDim.x * blockDim.x) {
        if (i < E) {
            int d = bd[i]; int pos = atomicAdd(&cu[d], 1);
            bso[pos] = bs[i]; bto[pos] = bt[i]; bdo_[pos] = d;
        } else {
            int k = i - E;
            int d = pd[k]; int pos = atomicAdd(&ci[d], 1);
            pso[pos] = ps[k]; pto[pos] = pt[k]; pdo_[pos] = d;
        }
    }
}

// ============================ transform (both tables; round-3-proven 4-scalar-row form) ============
__global__ __launch_bounds__(256) void k_transform2(
    const float* __restrict__ user_h, const float* __restrict__ item_h,
    const float* __restrict__ Wu_l, const float* __restrict__ Wi_l,
    unsigned short* __restrict__ uh, unsigned short* __restrict__ ih,
    int NU, int NI, int TB) {
    bool rel = blockIdx.x >= (unsigned)TB;
    int b = rel ? blockIdx.x - TB : blockIdx.x;
    const float* in = rel ? item_h : user_h;
    const float* W  = rel ? Wi_l : Wu_l;
    unsigned short* out = rel ? ih : uh;
    int n = rel ? NI : NU;
    __shared__ float Ws[D * D];
    int t = threadIdx.x;
#pragma unroll
    for (int i = 0; i < 16; ++i) Ws[i * 256 + t] = W[i * 256 + t];
    __syncthreads();
    int lane = t & 63, wid = t >> 6;
    int base = b * 16 + wid * 4;
    float iv0 = (base + 0 < n) ? in[(size_t)(base + 0) * D + lane] : 0.f;
    float iv1 = (base + 1 < n) ? in[(size_t)(base + 1) * D + lane] : 0.f;
    float iv2 = (base + 2 < n) ? in[(size_t)(base + 2) * D + lane] : 0.f;
    float iv3 = (base + 3 < n) ? in[(size_t)(base + 3) * D + lane] : 0.f;
    float o0 = 0.f, o1 = 0.f, o2 = 0.f, o3 = 0.f;
#pragma unroll
    for (int d = 0; d < D; ++d) {
        float w = Ws[d * D + lane];
        o0 += __shfl(iv0, d) * w;
        o1 += __shfl(iv1, d) * w;
        o2 += __shfl(iv2, d) * w;
        o3 += __shfl(iv3, d) * w;
    }
    if (base + 0 < n) out[(size_t)(base + 0) * D + lane] = f2bf(o0);
    if (base + 1 < n) out[(size_t)(base + 1) * D + lane] = f2bf(o1);
    if (base + 2 < n) out[(size_t)(base + 2) * D + lane] = f2bf(o2);
    if (base + 3 < n) out[(size_t)(base + 3) * D + lane] = f2bf(o3);
}

// ============================ edge kernel: 16-lane groups, 4 edges/wave ============================
__global__ __launch_bounds__(256) void k_edge2(
    const unsigned short* __restrict__ ihF, const unsigned short* __restrict__ uhF,
    const int* __restrict__ by_s, const int* __restrict__ by_d, const float* __restrict__ by_t,
    const int* __restrict__ pby_s, const int* __restrict__ pby_d, const float* __restrict__ pby_t,
    const float* __restrict__ uf, const float* __restrict__ up,
    const float* __restrict__ ukf, const float* __restrict__ ukp,
    const float* __restrict__ ifq, const float* __restrict__ ipq,
    const float* __restrict__ ikf, const float* __restrict__ ikp,
    float* __restrict__ agg_u, float* __restrict__ den_u,
    float* __restrict__ agg_i, float* __restrict__ den_i,
    int E, int EB) {
    bool rel = blockIdx.x >= (unsigned)EB;  // false: 'by' item->user, true: 'pby' user->item
    int rblk = rel ? blockIdx.x - EB : blockIdx.x;
    const unsigned short* srcF = rel ? uhF : ihF;
    const unsigned short* dstF = rel ? ihF : uhF;
    const int* es = rel ? pby_s : by_s;
    const int* ed = rel ? pby_d : by_d;
    const float* et = rel ? pby_t : by_t;
    const float* efq = rel ? ifq : uf;
    const float* eps = rel ? ipq : up;
    const float* kfq = rel ? ikf : ukf;
    const float* kps = rel ? ikp : ukp;
    float* agg = rel ? agg_i : agg_u;
    float* den = rel ? den_i : den_u;

    int lane = threadIdx.x & 15;
    int grp  = threadIdx.x >> 4;
    int base = rblk * 256 + grp * 16;
    if (base >= E) return;
    float4 ef4 = ((const float4*)efq)[lane];
    float4 ep4 = ((const float4*)eps)[lane];
    float4 kf4 = ((const float4*)kfq)[lane];
    float4 kp4 = ((const float4*)kps)[lane];
    bool same = ef4.x == kf4.x && ef4.y == kf4.y && ef4.z == kf4.z && ef4.w == kf4.w &&
                ep4.x == kp4.x && ep4.y == kp4.y && ep4.z == kp4.z && ep4.w == kp4.w;
    same = __all(same);  // uniform: key time-encode identical to e time-encode

    float a0 = 0, a1 = 0, a2 = 0, a3 = 0, dn = 0;
    float d0 = 0, d1 = 0, d2 = 0, d3 = 0;
    int cur = -1;
    for (int j = 0; j < 16; ++j) {
        int e = base + j;
        if (e >= E) break;
        int s = es[e]; int dd = ed[e]; float t = et[e];
        if (dd != cur) {  // group-uniform
            if (cur >= 0) {
                float* ap = &agg[(size_t)cur * D + lane * 4];
                unsafeAtomicAdd(ap + 0, a0); unsafeAtomicAdd(ap + 1, a1);
                unsafeAtomicAdd(ap + 2, a2); unsafeAtomicAdd(ap + 3, a3);
                if (lane == 0) unsafeAtomicAdd(&den[cur], dn);
            }
            a0 = a1 = a2 = a3 = 0; dn = 0; cur = dd;
            ushort4 dq = *(const ushort4*)&dstF[(size_t)dd * D + lane * 4];
            d0 = bf2f(dq.x); d1 = bf2f(dq.y); d2 = bf2f(dq.z); d3 = bf2f(dq.w);
        }
        ushort4 sq = *(const ushort4*)&srcF[(size_t)s * D + lane * 4];
        float s0 = bf2f(sq.x), s1 = bf2f(sq.y), s2 = bf2f(sq.z), s3 = bf2f(sq.w);
        float c0 = __cosf(fmaf(t, ef4.x, ep4.x));
        float c1 = __cosf(fmaf(t, ef4.y, ep4.y));
        float c2 = __cosf(fmaf(t, ef4.z, ep4.z));
        float c3 = __cosf(fmaf(t, ef4.w, ep4.w));
        float p = (c0 + s0) * d0 + (c1 + s1) * d1 + (c2 + s2) * d2 + (c3 + s3) * d3;
        p += __shfl_xor(p, 1); p += __shfl_xor(p, 2);
        p += __shfl_xor(p, 4); p += __shfl_xor(p, 8);
        float ex = __expf(p * 0.125f);
        float k0, k1, k2, k3;
        if (same) { k0 = c0; k1 = c1; k2 = c2; k3 = c3; }
        else {
            k0 = __cosf(fmaf(t, kf4.x, kp4.x)); k1 = __cosf(fmaf(t, kf4.y, kp4.y));
            k2 = __cosf(fmaf(t, kf4.z, kp4.z)); k3 = __cosf(fmaf(t, kf4.w, kp4.w));
        }
        a0 = fmaf(ex, s0 + k0, a0); a1 = fmaf(ex, s1 + k1, a1);
        a2 = fmaf(ex, s2 + k2, a2); a3 = fmaf(ex, s3 + k3, a3);
        dn += ex;
    }
    if (cur >= 0) {
        float* ap = &agg[(size_t)cur * D + lane * 4];
        unsafeAtomicAdd(ap + 0, a0); unsafeAtomicAdd(ap + 1, a1);
        unsafeAtomicAdd(ap + 2, a2); unsafeAtomicAdd(ap + 3, a3);
        if (lane == 0) unsafeAtomicAdd(&den[cur], dn);
    }
}

// ============================ update: LDS-row form (round-3-proven), 16 rows/block ================
// Each wave owns 4 rows staged in LDS (wave-private -> broadcast reads are free);
// scalar accumulators only. No shfl batching (round-4 spill lesson).
__global__ __launch_bounds__(256) void k_update2(
    float* __restrict__ user_h, float* __restrict__ item_h,
    const float* __restrict__ agg_u, const float* __restrict__ den_u,
    const float* __restrict__ agg_i, const float* __restrict__ den_i,
    const float* __restrict__ Wuu_l, const float* __restrict__ Wii_l,
    int NU, int NI, int UB) {
    bool rel = blockIdx.x >= (unsigned)UB;
    int b = rel ? blockIdx.x - UB : blockIdx.x;
    float* h = rel ? item_h : user_h;
    const float* agg = rel ? agg_i : agg_u;
    const float* den = rel ? den_i : den_u;
    const float* W2  = rel ? Wii_l : Wuu_l;
    int n = rel ? NI : NU;
    __shared__ float Ws[2 * D * D];      // 32 KB
    __shared__ float rows[16][2 * D];    // 8 KB
    int t = threadIdx.x;
#pragma unroll
    for (int i = 0; i < 32; ++i) Ws[i * 256 + t] = W2[i * 256 + t];
    int lane = t & 63, wid = t >> 6;
    int rbase = b * 16 + wid * 4;
#pragma unroll
    for (int r = 0; r < 4; ++r) {
        int row = rbase + r;
        float a = 0.f, hv = 0.f;
        if (row < n) {
            float dd = den[row];
            float inv = dd > 0.f ? 1.f / dd : 0.f;  // empty segment -> zeros
            a = agg[(size_t)row * D + lane] * inv;
            hv = h[(size_t)row * D + lane];
        }
        rows[wid * 4 + r][lane] = a;
        rows[wid * 4 + r][D + lane] = hv;
    }
    __syncthreads();
    const float* r0 = rows[wid * 4 + 0];
    const float* r1 = rows[wid * 4 + 1];
    const float* r2 = rows[wid * 4 + 2];
    const float* r3 = rows[wid * 4 + 3];
    float o0 = 0.f, o1 = 0.f, o2 = 0.f, o3 = 0.f;
#pragma unroll 8
    for (int d = 0; d < 2 * D; ++d) {
        float w = Ws[d * D + lane];
        o0 = fmaf(r0[d], w, o0);
        o1 = fmaf(r1[d], w, o1);
        o2 = fmaf(r2[d], w, o2);
        o3 = fmaf(r3[d], w, o3);
    }
    if (rbase + 0 < n) h[(size_t)(rbase + 0) * D + lane] = o0 > 0.f ? o0 : __expf(o0) - 1.f;
    if (rbase + 1 < n) h[(size_t)(rbase + 1) * D + lane] = o1 > 0.f ? o1 : __expf(o1) - 1.f;
    if (rbase + 2 < n) h[(size_t)(rbase + 2) * D + lane] = o2 > 0.f ? o2 : __expf(o2) - 1.f;
    if (rbase + 3 < n) h[(size_t)(rbase + 3) * D + lane] = o3 > 0.f ? o3 : __expf(o3) - 1.f;
}

// ============================ tail ============================
__global__ __launch_bounds__(256) void k_gather_feat(const float* __restrict__ h,
                                                     const int* __restrict__ idx,
                                                     float* __restrict__ feat, int B,
                                                     int colOff, int FW) {
    int i = blockIdx.x * blockDim.x + threadIdx.x;
    if (i >= B * D) return;
    int b = i >> 6, c = i & 63;
    feat[(size_t)b * FW + colOff + c] = h[(size_t)idx[b] * D + c];
}

__global__ __launch_bounds__(64) void k_final(const float* __restrict__ feat,
                                              const float* __restrict__ uW,
                                              const float* __restrict__ dW,
                                              const float* __restrict__ db,
                                              float* __restrict__ out, int B, int FW) {
    __shared__ float fr[512];
    __shared__ float un[D];
    int b = blockIdx.x;
    int c = threadIdx.x;
    for (int i = c; i < FW; i += 64) fr[i] = feat[(size_t)b * FW + i];
    __syncthreads();
    float acc = 0.f;
    for (int d = 0; d < FW; ++d) acc += fr[d] * uW[d * D + c];
    un[c] = acc;
    __syncthreads();
    if (c < 3) {
        float o = db[c];
#pragma unroll
        for (int d = 0; d < D; ++d) o += un[d] * dW[d * 3 + c];
        out[b * 3 + c] = o > 0.f ? o : 0.f;
    }
}

// ============================ launch ============================
extern "C" void kernel_launch(void* const* d_in, const int* in_sizes, int n_in,
                              void* d_out, int out_size, void* d_ws, size_t ws_size,
                              hipStream_t stream) {
    const float* user_emb = (const float*)d_in[0];
    const float* item_emb = (const float*)d_in[1];
    const float* Wu       = (const float*)d_in[2];
    const float* Wi       = (const float*)d_in[3];
    const float* Wuu      = (const float*)d_in[4];
    const float* Wii      = (const float*)d_in[5];
    const float* u_freq   = (const float*)d_in[6];
    const float* u_phase  = (const float*)d_in[7];
    const float* uk_freq  = (const float*)d_in[8];
    const float* uk_phase = (const float*)d_in[9];
    const float* i_freq   = (const float*)d_in[10];
    const float* i_phase  = (const float*)d_in[11];
    const float* ik_freq  = (const float*)d_in[12];
    const float* ik_phase = (const float*)d_in[13];
    const float* unified_W = (const float*)d_in[14];
    const float* dense_W   = (const float*)d_in[15];
    const float* dense_b   = (const float*)d_in[16];
    const float* by_time   = (const float*)d_in[17];
    const float* pby_time  = (const float*)d_in[18];
    const int* user_id   = (const int*)d_in[19];
    const int* item_id   = (const int*)d_in[20];
    const int* by_src    = (const int*)d_in[21];
    const int* by_dst    = (const int*)d_in[22];
    const int* pby_src   = (const int*)d_in[23];
    const int* pby_dst   = (const int*)d_in[24];
    const int* user_index = (const int*)d_in[25];
    const int* last_item_index = (const int*)d_in[26];

    const int NU = in_sizes[19];
    const int NI = in_sizes[20];
    const int E  = in_sizes[21];
    const int B  = in_sizes[25];
    const int L  = in_sizes[2] / (D * D);
    const int FW = (L + 1) * D;

    // ---- workspace: [agg_u|agg_i|den_u|den_i] zeroed per layer; [cur_u|cur_i] zeroed once ----
    char* wp = (char*)d_ws;
    auto alloc_f = [&](size_t n) { float* p = (float*)wp; wp += n * sizeof(float); return p; };
    auto alloc_i = [&](size_t n) { int* p = (int*)wp; wp += n * sizeof(int); return p; };
    auto alloc_h = [&](size_t n) { unsigned short* p = (unsigned short*)wp; wp += n * sizeof(unsigned short); return p; };
    float* agg_u = alloc_f((size_t)NU * D);
    float* agg_i = alloc_f((size_t)NI * D);
    float* den_u = alloc_f(NU);
    float* den_i = alloc_f(NI);
    size_t zero_bytes = (size_t)(wp - (char*)d_ws);
    int* cur_u = alloc_i(NU);
    int* cur_i = alloc_i(NI);
    size_t cur_bytes = (size_t)NU * 4 + (size_t)NI * 4;
    float* user_h = alloc_f((size_t)NU * D);
    float* item_h = alloc_f((size_t)NI * D);
    unsigned short* uh = alloc_h((size_t)NU * D);
    unsigned short* ih = alloc_h((size_t)NI * D);
    int*   by_rowptr  = alloc_i(NU + 1);
    int*   by_srcs    = alloc_i(E);
    float* by_times   = alloc_f(E);
    int*   by_dsts    = alloc_i(E);
    int*   pby_rowptr = alloc_i(NI + 1);
    int*   pby_srcs   = alloc_i(E);
    float* pby_times  = alloc_f(E);
    int*   pby_dsts   = alloc_i(E);
    int*   bsums      = alloc_i(512);
    float* feat       = alloc_f((size_t)B * FW);

    const int nbU = (NU + 2047) / 2048, nbI = (NI + 2047) / 2048;

    // initial node features
    k_gather2<<<((NU + NI) * D + 255) / 256, 256, 0, stream>>>(
        user_emb, item_emb, user_id, item_id, user_h, item_h, NU, NI);

    // dst-sorted edge lists, both relations
    hipMemsetAsync(cur_u, 0, cur_bytes, stream);
    k_hist2<<<2048, 256, 0, stream>>>(by_dst, pby_dst, cur_u, cur_i, E);
    k_scan_block2<<<nbU + nbI, 256, 0, stream>>>(cur_u, by_rowptr, cur_i, pby_rowptr,
                                                 bsums, nbU, NU, NI);
    k_scan_small<<<1, 256, 0, stream>>>(bsums, nbU, nbI);
    k_fixup2<<<(NU + NI + 255) / 256, 256, 0, stream>>>(by_rowptr, pby_rowptr, bsums,
                                                        cur_u, cur_i, NU, NI, E, nbU);
    k_scatter2<<<2048, 256, 0, stream>>>(by_src, by_dst, by_time,
                                         pby_src, pby_dst, pby_time,
                                         cur_u, cur_i,
                                         by_srcs, by_times, by_dsts,
                                         pby_srcs, pby_times, pby_dsts, E);

    const int EB = (E + 255) / 256;
    const int TB = (NU + 15) / 16, TBI = (NI + 15) / 16;
    const int UB = (NU + 15) / 16, UBI = (NI + 15) / 16;
    for (int l = 0; l < L; ++l) {
        hipMemsetAsync(d_ws, 0, zero_bytes, stream);
        k_transform2<<<TB + TBI, 256, 0, stream>>>(user_h, item_h,
                                                   Wu + l * D * D, Wi + l * D * D,
                                                   uh, ih, NU, NI, TB);
        k_edge2<<<2 * EB, 256, 0, stream>>>(
            ih, uh,
            by_srcs, by_dsts, by_times,
            pby_srcs, pby_dsts, pby_times,
            u_freq + l * D, u_phase + l * D, uk_freq + l * D, uk_phase + l * D,
            i_freq + l * D, i_phase + l * D, ik_freq + l * D, ik_phase + l * D,
            agg_u, den_u, agg_i, den_i, E, EB);
        k_update2<<<UB + UBI, 256, 0, stream>>>(user_h, item_h,
                                                agg_u, den_u, agg_i, den_i,
                                                Wuu + (size_t)l * 2 * D * D,
                                                Wii + (size_t)l * 2 * D * D,
                                                NU, NI, UB);
        k_gather_feat<<<(B * D + 255) / 256, 256, 0, stream>>>(user_h, user_index, feat, B,
                                                               l * D, FW);
    }
    k_gather_feat<<<(B * D + 255) / 256, 256, 0, stream>>>(item_h, last_item_index, feat, B,
                                                           L * D, FW);
    k_final<<<B, 64, 0, stream>>>(feat, unified_W, dense_W, dense_b, (float*)d_out, B, FW);
}

// Round 6
// 1615.392 us; speedup vs baseline: 6.3716x; 1.3256x over previous
//
#include <hip/hip_runtime.h>
#include <math.h>

#define D 64

__device__ __forceinline__ float bf2f(unsigned short u) {
    union { unsigned int i; float f; } v; v.i = ((unsigned int)u) << 16; return v.f;
}
__device__ __forceinline__ unsigned short f2bf(float f) {
    union { float f; unsigned int i; } v; v.f = f;
    unsigned int r = v.i + 0x7FFFu + ((v.i >> 16) & 1u);
    return (unsigned short)(r >> 16);
}

// ============================ initial gather (both tables, one launch) ============================
__global__ __launch_bounds__(256) void k_gather2(const float* __restrict__ ue,
                                                 const float* __restrict__ ie,
                                                 const int* __restrict__ uid,
                                                 const int* __restrict__ iid,
                                                 float* __restrict__ uh0,
                                                 float* __restrict__ ih0, int NU, int NI) {
    int i = blockIdx.x * blockDim.x + threadIdx.x;
    if (i >= (NU + NI) * D) return;
    int r = i >> 6, c = i & 63;
    if (r < NU) uh0[(size_t)r * D + c] = ue[(size_t)uid[r] * D + c];
    else { int j = r - NU; ih0[(size_t)j * D + c] = ie[(size_t)iid[j] * D + c]; }
}

// ============================ CSR build (both relations per launch) ============================
__global__ __launch_bounds__(256) void k_hist2(const int* __restrict__ bd,
                                               const int* __restrict__ pd,
                                               int* __restrict__ cu, int* __restrict__ ci, int E) {
    for (int i = blockIdx.x * blockDim.x + threadIdx.x; i < 2 * E; i += gridDim.x * blockDim.x) {
        if (i < E) atomicAdd(&cu[bd[i]], 1);
        else       atomicAdd(&ci[pd[i - E]], 1);
    }
}

__global__ __launch_bounds__(256) void k_scan_block2(const int* __restrict__ cu, int* __restrict__ rp_u,
                                                     const int* __restrict__ ci, int* __restrict__ rp_i,
                                                     int* __restrict__ bsums, int nbU, int NU, int NI) {
    __shared__ int ts[256];
    bool rel = blockIdx.x >= (unsigned)nbU;
    const int* in = rel ? ci : cu;
    int* out = rel ? rp_i : rp_u;
    int n = rel ? NI : NU;
    int boff = rel ? blockIdx.x - nbU : blockIdx.x;
    int t = threadIdx.x;
    int base = boff * 2048 + t * 8;
    int v[8]; int s = 0;
#pragma unroll
    for (int k = 0; k < 8; ++k) { int idx = base + k; v[k] = idx < n ? in[idx] : 0; s += v[k]; }
    ts[t] = s; __syncthreads();
    for (int off = 1; off < 256; off <<= 1) {
        int x = (t >= off) ? ts[t - off] : 0;
        __syncthreads(); ts[t] += x; __syncthreads();
    }
    int excl = ts[t] - s;
    if (t == 255) bsums[blockIdx.x] = ts[255];
    int run = excl;
#pragma unroll
    for (int k = 0; k < 8; ++k) { int idx = base + k; if (idx < n) out[idx] = run; run += v[k]; }
}

// in-place exclusive scan of bsums, two segments [0,nbU) and [nbU,nbU+nbI), each <=128
__global__ __launch_bounds__(256) void k_scan_small(int* __restrict__ bsums, int nbU, int nbI) {
    __shared__ int ts[256];
    int t = threadIdx.x;
    int half = t >> 7, local = t & 127;
    int nb = half ? nbI : nbU;
    int g = half ? nbU + local : local;
    int v = local < nb ? bsums[g] : 0;
    ts[t] = v; __syncthreads();
    for (int off = 1; off < 128; off <<= 1) {
        int x = (local >= off) ? ts[t - off] : 0;
        __syncthreads(); ts[t] += x; __syncthreads();
    }
    if (local < nb) bsums[g] = ts[t] - v;
}

__global__ __launch_bounds__(256) void k_fixup2(int* __restrict__ rp_u, int* __restrict__ rp_i,
                                                const int* __restrict__ bsums,
                                                int* __restrict__ cu, int* __restrict__ ci,
                                                int NU, int NI, int E, int nbU) {
    int i = blockIdx.x * blockDim.x + threadIdx.x;
    if (i < NU) {
        int v = rp_u[i] + bsums[i >> 11]; rp_u[i] = v; cu[i] = v;
        if (i == 0) rp_u[NU] = E;
    } else if (i < NU + NI) {
        int j = i - NU;
        int v = rp_i[j] + bsums[nbU + (j >> 11)]; rp_i[j] = v; ci[j] = v;
        if (j == 0) rp_i[NI] = E;
    }
}

// scatter into dst-sorted order; (src,time) packed as int2
__global__ __launch_bounds__(256) void k_scatter2(
    const int* __restrict__ bs, const int* __restrict__ bd, const float* __restrict__ bt,
    const int* __restrict__ ps, const int* __restrict__ pd, const float* __restrict__ pt,
    int* __restrict__ cu, int* __restrict__ ci,
    int2* __restrict__ bst, int* __restrict__ bdo_,
    int2* __restrict__ pst, int* __restrict__ pdo_, int E) {
    for (int i = blockIdx.x * blockDim.x + threadIdx.x; i < 2 * E; i += gridDim.x * blockDim.x) {
        if (i < E) {
            int d = bd[i]; int pos = atomicAdd(&cu[d], 1);
            bst[pos] = make_int2(bs[i], __float_as_int(bt[i])); bdo_[pos] = d;
        } else {
            int k = i - E;
            int d = pd[k]; int pos = atomicAdd(&ci[d], 1);
            pst[pos] = make_int2(ps[k], __float_as_int(pt[k])); pdo_[pos] = d;
        }
    }
}

// ============================ transform (both tables; proven 4-scalar-row form) ============
__global__ __launch_bounds__(256) void k_transform2(
    const float* __restrict__ user_h, const float* __restrict__ item_h,
    const float* __restrict__ Wu_l, const float* __restrict__ Wi_l,
    unsigned short* __restrict__ uh, unsigned short* __restrict__ ih,
    int NU, int NI, int TB) {
    bool rel = blockIdx.x >= (unsigned)TB;
    int b = rel ? blockIdx.x - TB : blockIdx.x;
    const float* in = rel ? item_h : user_h;
    const float* W  = rel ? Wi_l : Wu_l;
    unsigned short* out = rel ? ih : uh;
    int n = rel ? NI : NU;
    __shared__ float Ws[D * D];
    int t = threadIdx.x;
#pragma unroll
    for (int i = 0; i < 16; ++i) Ws[i * 256 + t] = W[i * 256 + t];
    __syncthreads();
    int lane = t & 63, wid = t >> 6;
    int base = b * 16 + wid * 4;
    float iv0 = (base + 0 < n) ? in[(size_t)(base + 0) * D + lane] : 0.f;
    float iv1 = (base + 1 < n) ? in[(size_t)(base + 1) * D + lane] : 0.f;
    float iv2 = (base + 2 < n) ? in[(size_t)(base + 2) * D + lane] : 0.f;
    float iv3 = (base + 3 < n) ? in[(size_t)(base + 3) * D + lane] : 0.f;
    float o0 = 0.f, o1 = 0.f, o2 = 0.f, o3 = 0.f;
#pragma unroll
    for (int d = 0; d < D; ++d) {
        float w = Ws[d * D + lane];
        o0 += __shfl(iv0, d) * w;
        o1 += __shfl(iv1, d) * w;
        o2 += __shfl(iv2, d) * w;
        o3 += __shfl(iv3, d) * w;
    }
    if (base + 0 < n) out[(size_t)(base + 0) * D + lane] = f2bf(o0);
    if (base + 1 < n) out[(size_t)(base + 1) * D + lane] = f2bf(o1);
    if (base + 2 < n) out[(size_t)(base + 2) * D + lane] = f2bf(o2);
    if (base + 3 < n) out[(size_t)(base + 3) * D + lane] = f2bf(o3);
}

// ============================ edge kernel: 16-lane groups, strided dims ============================
// Lane covers dims {l, l+16, l+32, l+48}: each atomic-flush instruction writes
// 16 lanes x 4B contiguous = one fully-dirty 64B line (round-5 write-amplification fix).
__global__ __launch_bounds__(256) void k_edge2(
    const unsigned short* __restrict__ ihF, const unsigned short* __restrict__ uhF,
    const int2* __restrict__ by_st, const int* __restrict__ by_d,
    const int2* __restrict__ pby_st, const int* __restrict__ pby_d,
    const float* __restrict__ uf, const float* __restrict__ up,
    const float* __restrict__ ukf, const float* __restrict__ ukp,
    const float* __restrict__ ifq, const float* __restrict__ ipq,
    const float* __restrict__ ikf, const float* __restrict__ ikp,
    float* __restrict__ agg_u, float* __restrict__ den_u,
    float* __restrict__ agg_i, float* __restrict__ den_i,
    int E, int EB) {
    bool rel = blockIdx.x >= (unsigned)EB;  // false: 'by' item->user, true: 'pby' user->item
    int rblk = rel ? blockIdx.x - EB : blockIdx.x;
    const unsigned short* srcF = rel ? uhF : ihF;
    const unsigned short* dstF = rel ? ihF : uhF;
    const int2* est = rel ? pby_st : by_st;
    const int* ed = rel ? pby_d : by_d;
    const float* efq = rel ? ifq : uf;
    const float* eps = rel ? ipq : up;
    const float* kfq = rel ? ikf : ukf;
    const float* kps = rel ? ikp : ukp;
    float* agg = rel ? agg_i : agg_u;
    float* den = rel ? den_i : den_u;

    int lane = threadIdx.x & 15;
    int grp  = threadIdx.x >> 4;
    int base = rblk * 256 + grp * 16;
    if (base >= E) return;
    float ef0 = efq[lane], ef1 = efq[lane + 16], ef2 = efq[lane + 32], ef3 = efq[lane + 48];
    float ep0 = eps[lane], ep1 = eps[lane + 16], ep2 = eps[lane + 32], ep3 = eps[lane + 48];
    float kf0 = kfq[lane], kf1 = kfq[lane + 16], kf2 = kfq[lane + 32], kf3 = kfq[lane + 48];
    float kp0 = kps[lane], kp1 = kps[lane + 16], kp2 = kps[lane + 32], kp3 = kps[lane + 48];
    bool same = ef0 == kf0 && ef1 == kf1 && ef2 == kf2 && ef3 == kf3 &&
                ep0 == kp0 && ep1 == kp1 && ep2 == kp2 && ep3 == kp3;
    same = __all(same);  // uniform: key time-encode identical to e time-encode

    float a0 = 0, a1 = 0, a2 = 0, a3 = 0, dn = 0;
    float d0 = 0, d1 = 0, d2 = 0, d3 = 0;
    int cur = -1;
    for (int j = 0; j < 16; ++j) {
        int e = base + j;
        if (e >= E) break;
        int2 st = est[e];
        int s = st.x; float t = __int_as_float(st.y);
        int dd = ed[e];
        if (dd != cur) {  // group-uniform
            if (cur >= 0) {
                float* ap = &agg[(size_t)cur * D + lane];
                unsafeAtomicAdd(ap +  0, a0); unsafeAtomicAdd(ap + 16, a1);
                unsafeAtomicAdd(ap + 32, a2); unsafeAtomicAdd(ap + 48, a3);
                if (lane == 0) unsafeAtomicAdd(&den[cur], dn);
            }
            a0 = a1 = a2 = a3 = 0; dn = 0; cur = dd;
            const unsigned short* dp = &dstF[(size_t)dd * D + lane];
            d0 = bf2f(dp[0]); d1 = bf2f(dp[16]); d2 = bf2f(dp[32]); d3 = bf2f(dp[48]);
        }
        const unsigned short* sp = &srcF[(size_t)s * D + lane];
        float s0 = bf2f(sp[0]), s1 = bf2f(sp[16]), s2 = bf2f(sp[32]), s3 = bf2f(sp[48]);
        float c0 = __cosf(fmaf(t, ef0, ep0));
        float c1 = __cosf(fmaf(t, ef1, ep1));
        float c2 = __cosf(fmaf(t, ef2, ep2));
        float c3 = __cosf(fmaf(t, ef3, ep3));
        float p = (c0 + s0) * d0 + (c1 + s1) * d1 + (c2 + s2) * d2 + (c3 + s3) * d3;
        p += __shfl_xor(p, 1); p += __shfl_xor(p, 2);
        p += __shfl_xor(p, 4); p += __shfl_xor(p, 8);
        float ex = __expf(p * 0.125f);
        float k0, k1, k2, k3;
        if (same) { k0 = c0; k1 = c1; k2 = c2; k3 = c3; }
        else {
            k0 = __cosf(fmaf(t, kf0, kp0)); k1 = __cosf(fmaf(t, kf1, kp1));
            k2 = __cosf(fmaf(t, kf2, kp2)); k3 = __cosf(fmaf(t, kf3, kp3));
        }
        a0 = fmaf(ex, s0 + k0, a0); a1 = fmaf(ex, s1 + k1, a1);
        a2 = fmaf(ex, s2 + k2, a2); a3 = fmaf(ex, s3 + k3, a3);
        dn += ex;
    }
    if (cur >= 0) {
        float* ap = &agg[(size_t)cur * D + lane];
        unsafeAtomicAdd(ap +  0, a0); unsafeAtomicAdd(ap + 16, a1);
        unsafeAtomicAdd(ap + 32, a2); unsafeAtomicAdd(ap + 48, a3);
        if (lane == 0) unsafeAtomicAdd(&den[cur], dn);
    }
}

// ============================ update: LDS-row form, 16 rows/block ================
__global__ __launch_bounds__(256) void k_update2(
    float* __restrict__ user_h, float* __restrict__ item_h,
    const float* __restrict__ agg_u, const float* __restrict__ den_u,
    const float* __restrict__ agg_i, const float* __restrict__ den_i,
    const float* __restrict__ Wuu_l, const float* __restrict__ Wii_l,
    int NU, int NI, int UB) {
    bool rel = blockIdx.x >= (unsigned)UB;
    int b = rel ? blockIdx.x - UB : blockIdx.x;
    float* h = rel ? item_h : user_h;
    const float* agg = rel ? agg_i : agg_u;
    const float* den = rel ? den_i : den_u;
    const float* W2  = rel ? Wii_l : Wuu_l;
    int n = rel ? NI : NU;
    __shared__ float Ws[2 * D * D];      // 32 KB
    __shared__ float rows[16][2 * D];    // 8 KB
    int t = threadIdx.x;
#pragma unroll
    for (int i = 0; i < 32; ++i) Ws[i * 256 + t] = W2[i * 256 + t];
    int lane = t & 63, wid = t >> 6;
    int rbase = b * 16 + wid * 4;
#pragma unroll
    for (int r = 0; r < 4; ++r) {
        int row = rbase + r;
        float a = 0.f, hv = 0.f;
        if (row < n) {
            float dd = den[row];
            float inv = dd > 0.f ? 1.f / dd : 0.f;  // empty segment -> zeros
            a = agg[(size_t)row * D + lane] * inv;
            hv = h[(size_t)row * D + lane];
        }
        rows[wid * 4 + r][lane] = a;
        rows[wid * 4 + r][D + lane] = hv;
    }
    __syncthreads();
    const float* r0 = rows[wid * 4 + 0];
    const float* r1 = rows[wid * 4 + 1];
    const float* r2 = rows[wid * 4 + 2];
    const float* r3 = rows[wid * 4 + 3];
    float o0 = 0.f, o1 = 0.f, o2 = 0.f, o3 = 0.f;
#pragma unroll 8
    for (int d = 0; d < 2 * D; ++d) {
        float w = Ws[d * D + lane];
        o0 = fmaf(r0[d], w, o0);
        o1 = fmaf(r1[d], w, o1);
        o2 = fmaf(r2[d], w, o2);
        o3 = fmaf(r3[d], w, o3);
    }
    if (rbase + 0 < n) h[(size_t)(rbase + 0) * D + lane] = o0 > 0.f ? o0 : __expf(o0) - 1.f;
    if (rbase + 1 < n) h[(size_t)(rbase + 1) * D + lane] = o1 > 0.f ? o1 : __expf(o1) - 1.f;
    if (rbase + 2 < n) h[(size_t)(rbase + 2) * D + lane] = o2 > 0.f ? o2 : __expf(o2) - 1.f;
    if (rbase + 3 < n) h[(size_t)(rbase + 3) * D + lane] = o3 > 0.f ? o3 : __expf(o3) - 1.f;
}

// ============================ tail ============================
__global__ __launch_bounds__(256) void k_gather_feat(const float* __restrict__ h,
                                                     const int* __restrict__ idx,
                                                     float* __restrict__ feat, int B,
                                                     int colOff, int FW) {
    int i = blockIdx.x * blockDim.x + threadIdx.x;
    if (i >= B * D) return;
    int b = i >> 6, c = i & 63;
    feat[(size_t)b * FW + colOff + c] = h[(size_t)idx[b] * D + c];
}

__global__ __launch_bounds__(64) void k_final(const float* __restrict__ feat,
                                              const float* __restrict__ uW,
                                              const float* __restrict__ dW,
                                              const float* __restrict__ db,
                                              float* __restrict__ out, int B, int FW) {
    __shared__ float fr[512];
    __shared__ float un[D];
    int b = blockIdx.x;
    int c = threadIdx.x;
    for (int i = c; i < FW; i += 64) fr[i] = feat[(size_t)b * FW + i];
    __syncthreads();
    float acc = 0.f;
    for (int d = 0; d < FW; ++d) acc += fr[d] * uW[d * D + c];
    un[c] = acc;
    __syncthreads();
    if (c < 3) {
        float o = db[c];
#pragma unroll
        for (int d = 0; d < D; ++d) o += un[d] * dW[d * 3 + c];
        out[b * 3 + c] = o > 0.f ? o : 0.f;
    }
}

// ============================ launch ============================
extern "C" void kernel_launch(void* const* d_in, const int* in_sizes, int n_in,
                              void* d_out, int out_size, void* d_ws, size_t ws_size,
                              hipStream_t stream) {
    const float* user_emb = (const float*)d_in[0];
    const float* item_emb = (const float*)d_in[1];
    const float* Wu       = (const float*)d_in[2];
    const float* Wi       = (const float*)d_in[3];
    const float* Wuu      = (const float*)d_in[4];
    const float* Wii      = (const float*)d_in[5];
    const float* u_freq   = (const float*)d_in[6];
    const float* u_phase  = (const float*)d_in[7];
    const float* uk_freq  = (const float*)d_in[8];
    const float* uk_phase = (const float*)d_in[9];
    const float* i_freq   = (const float*)d_in[10];
    const float* i_phase  = (const float*)d_in[11];
    const float* ik_freq  = (const float*)d_in[12];
    const float* ik_phase = (const float*)d_in[13];
    const float* unified_W = (const float*)d_in[14];
    const float* dense_W   = (const float*)d_in[15];
    const float* dense_b   = (const float*)d_in[16];
    const float* by_time   = (const float*)d_in[17];
    const float* pby_time  = (const float*)d_in[18];
    const int* user_id   = (const int*)d_in[19];
    const int* item_id   = (const int*)d_in[20];
    const int* by_src    = (const int*)d_in[21];
    const int* by_dst    = (const int*)d_in[22];
    const int* pby_src   = (const int*)d_in[23];
    const int* pby_dst   = (const int*)d_in[24];
    const int* user_index = (const int*)d_in[25];
    const int* last_item_index = (const int*)d_in[26];

    const int NU = in_sizes[19];
    const int NI = in_sizes[20];
    const int E  = in_sizes[21];
    const int B  = in_sizes[25];
    const int L  = in_sizes[2] / (D * D);
    const int FW = (L + 1) * D;

    // ---- workspace: [agg_u|agg_i|den_u|den_i] zeroed per layer; [cur_u|cur_i] zeroed once ----
    char* wp = (char*)d_ws;
    auto alloc_f = [&](size_t n) { float* p = (float*)wp; wp += n * sizeof(float); return p; };
    auto alloc_i = [&](size_t n) { int* p = (int*)wp; wp += n * sizeof(int); return p; };
    auto alloc_i2 = [&](size_t n) { int2* p = (int2*)wp; wp += n * sizeof(int2); return p; };
    auto alloc_h = [&](size_t n) { unsigned short* p = (unsigned short*)wp; wp += n * sizeof(unsigned short); return p; };
    float* agg_u = alloc_f((size_t)NU * D);
    float* agg_i = alloc_f((size_t)NI * D);
    float* den_u = alloc_f(NU);
    float* den_i = alloc_f(NI);
    size_t zero_bytes = (size_t)(wp - (char*)d_ws);
    int2* by_st  = alloc_i2(E);     // 8B-aligned (all prior sizes are multiples of 8)
    int2* pby_st = alloc_i2(E);
    int* cur_u = alloc_i(NU);
    int* cur_i = alloc_i(NI);
    size_t cur_bytes = (size_t)NU * 4 + (size_t)NI * 4;
    float* user_h = alloc_f((size_t)NU * D);
    float* item_h = alloc_f((size_t)NI * D);
    unsigned short* uh = alloc_h((size_t)NU * D);
    unsigned short* ih = alloc_h((size_t)NI * D);
    int*   by_dsts    = alloc_i(E);
    int*   pby_dsts   = alloc_i(E);
    int*   by_rowptr  = alloc_i(NU + 2);
    int*   pby_rowptr = alloc_i(NI + 2);
    int*   bsums      = alloc_i(512);
    float* feat       = alloc_f((size_t)B * FW);

    const int nbU = (NU + 2047) / 2048, nbI = (NI + 2047) / 2048;

    // initial node features
    k_gather2<<<((NU + NI) * D + 255) / 256, 256, 0, stream>>>(
        user_emb, item_emb, user_id, item_id, user_h, item_h, NU, NI);

    // dst-sorted edge lists, both relations
    hipMemsetAsync(cur_u, 0, cur_bytes, stream);
    k_hist2<<<2048, 256, 0, stream>>>(by_dst, pby_dst, cur_u, cur_i, E);
    k_scan_block2<<<nbU + nbI, 256, 0, stream>>>(cur_u, by_rowptr, cur_i, pby_rowptr,
                                                 bsums, nbU, NU, NI);
    k_scan_small<<<1, 256, 0, stream>>>(bsums, nbU, nbI);
    k_fixup2<<<(NU + NI + 255) / 256, 256, 0, stream>>>(by_rowptr, pby_rowptr, bsums,
                                                        cur_u, cur_i, NU, NI, E, nbU);
    k_scatter2<<<2048, 256, 0, stream>>>(by_src, by_dst, by_time,
                                         pby_src, pby_dst, pby_time,
                                         cur_u, cur_i,
                                         by_st, by_dsts,
                                         pby_st, pby_dsts, E);

    const int EB = (E + 255) / 256;
    const int TB = (NU + 15) / 16, TBI = (NI + 15) / 16;
    const int UB = (NU + 15) / 16, UBI = (NI + 15) / 16;
    for (int l = 0; l < L; ++l) {
        hipMemsetAsync(d_ws, 0, zero_bytes, stream);
        k_transform2<<<TB + TBI, 256, 0, stream>>>(user_h, item_h,
                                                   Wu + l * D * D, Wi + l * D * D,
                                                   uh, ih, NU, NI, TB);
        k_edge2<<<2 * EB, 256, 0, stream>>>(
            ih, uh,
            by_st, by_dsts,
            pby_st, pby_dsts,
            u_freq + l * D, u_phase + l * D, uk_freq + l * D, uk_phase + l * D,
            i_freq + l * D, i_phase + l * D, ik_freq + l * D, ik_phase + l * D,
            agg_u, den_u, agg_i, den_i, E, EB);
        k_update2<<<UB + UBI, 256, 0, stream>>>(user_h, item_h,
                                                agg_u, den_u, agg_i, den_i,
                                                Wuu + (size_t)l * 2 * D * D,
                                                Wii + (size_t)l * 2 * D * D,
                                                NU, NI, UB);
        k_gather_feat<<<(B * D + 255) / 256, 256, 0, stream>>>(user_h, user_index, feat, B,
                                                               l * D, FW);
    }
    k_gather_feat<<<(B * D + 255) / 256, 256, 0, stream>>>(item_h, last_item_index, feat, B,
                                                           L * D, FW);
    k_final<<<B, 64, 0, stream>>>(feat, unified_W, dense_W, dense_b, (float*)d_out, B, FW);
}

// Round 7
// 1527.797 us; speedup vs baseline: 6.7369x; 1.0573x over previous
//
#include <hip/hip_runtime.h>
#include <math.h>

#define D 64

__device__ __forceinline__ float bf2f(unsigned short u) {
    union { unsigned int i; float f; } v; v.i = ((unsigned int)u) << 16; return v.f;
}
__device__ __forceinline__ unsigned short f2bf(float f) {
    union { float f; unsigned int i; } v; v.f = f;
    unsigned int r = v.i + 0x7FFFu + ((v.i >> 16) & 1u);
    return (unsigned short)(r >> 16);
}

// ============================ initial gather (both tables, one launch) ============================
__global__ __launch_bounds__(256) void k_gather2(const float* __restrict__ ue,
                                                 const float* __restrict__ ie,
                                                 const int* __restrict__ uid,
                                                 const int* __restrict__ iid,
                                                 float* __restrict__ uh0,
                                                 float* __restrict__ ih0, int NU, int NI) {
    int i = blockIdx.x * blockDim.x + threadIdx.x;
    if (i >= (NU + NI) * D) return;
    int r = i >> 6, c = i & 63;
    if (r < NU) uh0[(size_t)r * D + c] = ue[(size_t)uid[r] * D + c];
    else { int j = r - NU; ih0[(size_t)j * D + c] = ie[(size_t)iid[j] * D + c]; }
}

// ============================ CSR build (both relations per launch) ============================
__global__ __launch_bounds__(256) void k_hist2(const int* __restrict__ bd,
                                               const int* __restrict__ pd,
                                               int* __restrict__ cu, int* __restrict__ ci, int E) {
    for (int i = blockIdx.x * blockDim.x + threadIdx.x; i < 2 * E; i += gridDim.x * blockDim.x) {
        if (i < E) atomicAdd(&cu[bd[i]], 1);
        else       atomicAdd(&ci[pd[i - E]], 1);
    }
}

__global__ __launch_bounds__(256) void k_scan_block2(const int* __restrict__ cu, int* __restrict__ rp_u,
                                                     const int* __restrict__ ci, int* __restrict__ rp_i,
                                                     int* __restrict__ bsums, int nbU, int NU, int NI) {
    __shared__ int ts[256];
    bool rel = blockIdx.x >= (unsigned)nbU;
    const int* in = rel ? ci : cu;
    int* out = rel ? rp_i : rp_u;
    int n = rel ? NI : NU;
    int boff = rel ? blockIdx.x - nbU : blockIdx.x;
    int t = threadIdx.x;
    int base = boff * 2048 + t * 8;
    int v[8]; int s = 0;
#pragma unroll
    for (int k = 0; k < 8; ++k) { int idx = base + k; v[k] = idx < n ? in[idx] : 0; s += v[k]; }
    ts[t] = s; __syncthreads();
    for (int off = 1; off < 256; off <<= 1) {
        int x = (t >= off) ? ts[t - off] : 0;
        __syncthreads(); ts[t] += x; __syncthreads();
    }
    int excl = ts[t] - s;
    if (t == 255) bsums[blockIdx.x] = ts[255];
    int run = excl;
#pragma unroll
    for (int k = 0; k < 8; ++k) { int idx = base + k; if (idx < n) out[idx] = run; run += v[k]; }
}

// in-place exclusive scan of bsums, two segments [0,nbU) and [nbU,nbU+nbI), each <=128
__global__ __launch_bounds__(256) void k_scan_small(int* __restrict__ bsums, int nbU, int nbI) {
    __shared__ int ts[256];
    int t = threadIdx.x;
    int half = t >> 7, local = t & 127;
    int nb = half ? nbI : nbU;
    int g = half ? nbU + local : local;
    int v = local < nb ? bsums[g] : 0;
    ts[t] = v; __syncthreads();
    for (int off = 1; off < 128; off <<= 1) {
        int x = (local >= off) ? ts[t - off] : 0;
        __syncthreads(); ts[t] += x; __syncthreads();
    }
    if (local < nb) bsums[g] = ts[t] - v;
}

__global__ __launch_bounds__(256) void k_fixup2(int* __restrict__ rp_u, int* __restrict__ rp_i,
                                                const int* __restrict__ bsums,
                                                int* __restrict__ cu, int* __restrict__ ci,
                                                int NU, int NI, int E, int nbU) {
    int i = blockIdx.x * blockDim.x + threadIdx.x;
    if (i < NU) {
        int v = rp_u[i] + bsums[i >> 11]; rp_u[i] = v; cu[i] = v;
        if (i == 0) rp_u[NU] = E;
    } else if (i < NU + NI) {
        int j = i - NU;
        int v = rp_i[j] + bsums[nbU + (j >> 11)]; rp_i[j] = v; ci[j] = v;
        if (j == 0) rp_i[NI] = E;
    }
}

// scatter into dst-sorted order; (src,time) packed as int2
__global__ __launch_bounds__(256) void k_scatter2(
    const int* __restrict__ bs, const int* __restrict__ bd, const float* __restrict__ bt,
    const int* __restrict__ ps, const int* __restrict__ pd, const float* __restrict__ pt,
    int* __restrict__ cu, int* __restrict__ ci,
    int2* __restrict__ bst, int* __restrict__ bdo_,
    int2* __restrict__ pst, int* __restrict__ pdo_, int E) {
    for (int i = blockIdx.x * blockDim.x + threadIdx.x; i < 2 * E; i += gridDim.x * blockDim.x) {
        if (i < E) {
            int d = bd[i]; int pos = atomicAdd(&cu[d], 1);
            bst[pos] = make_int2(bs[i], __float_as_int(bt[i])); bdo_[pos] = d;
        } else {
            int k = i - E;
            int d = pd[k]; int pos = atomicAdd(&ci[d], 1);
            pst[pos] = make_int2(ps[k], __float_as_int(pt[k])); pdo_[pos] = d;
        }
    }
}

// ============================ transform: W-in-VGPR, broadcast-row GEMM ============================
// Lane j holds W[:, j] in 64 VGPRs (static indexing only). Row values come from
// same-address global float4 loads (L2 broadcast). No LDS, no shfl (round-6 lesson:
// shfl-broadcast GEMM is DS-pipe-bound + VGPR-bloated).
__global__ __launch_bounds__(256) void k_transform3(
    const float* __restrict__ user_h, const float* __restrict__ item_h,
    const float* __restrict__ Wu_l, const float* __restrict__ Wi_l,
    unsigned short* __restrict__ uh, unsigned short* __restrict__ ih,
    int NU, int NI, int G) {
    bool rel = blockIdx.x >= (unsigned)G;
    int b = rel ? blockIdx.x - G : blockIdx.x;
    const float* in = rel ? item_h : user_h;
    const float* W  = rel ? Wi_l : Wu_l;
    unsigned short* out = rel ? ih : uh;
    int n = rel ? NI : NU;
    int lane = threadIdx.x & 63;
    int gw = b * 4 + (threadIdx.x >> 6);      // wave id within table
    int nw = G * 4;                           // waves per table
    float w[D];
#pragma unroll
    for (int d = 0; d < D; ++d) w[d] = W[d * D + lane];
    for (int row = gw; row < n; row += nw) {
        const float4* rp = (const float4*)&in[(size_t)row * D];
        float acc = 0.f;
#pragma unroll
        for (int c = 0; c < 16; ++c) {
            float4 v = rp[c];                 // same addr across lanes -> broadcast
            acc = fmaf(v.x, w[4 * c + 0], acc);
            acc = fmaf(v.y, w[4 * c + 1], acc);
            acc = fmaf(v.z, w[4 * c + 2], acc);
            acc = fmaf(v.w, w[4 * c + 3], acc);
        }
        out[(size_t)row * D + lane] = f2bf(acc);
    }
}

// ============================ edge kernel: 16-lane groups, strided dims ============================
// Lane covers dims {l, l+16, l+32, l+48}: each atomic-flush instruction writes
// 16 lanes x 4B contiguous = one fully-dirty 64B line (round-5 write-amplification fix).
__global__ __launch_bounds__(256) void k_edge2(
    const unsigned short* __restrict__ ihF, const unsigned short* __restrict__ uhF,
    const int2* __restrict__ by_st, const int* __restrict__ by_d,
    const int2* __restrict__ pby_st, const int* __restrict__ pby_d,
    const float* __restrict__ uf, const float* __restrict__ up,
    const float* __restrict__ ukf, const float* __restrict__ ukp,
    const float* __restrict__ ifq, const float* __restrict__ ipq,
    const float* __restrict__ ikf, const float* __restrict__ ikp,
    float* __restrict__ agg_u, float* __restrict__ den_u,
    float* __restrict__ agg_i, float* __restrict__ den_i,
    int E, int EB) {
    bool rel = blockIdx.x >= (unsigned)EB;  // false: 'by' item->user, true: 'pby' user->item
    int rblk = rel ? blockIdx.x - EB : blockIdx.x;
    const unsigned short* srcF = rel ? uhF : ihF;
    const unsigned short* dstF = rel ? ihF : uhF;
    const int2* est = rel ? pby_st : by_st;
    const int* ed = rel ? pby_d : by_d;
    const float* efq = rel ? ifq : uf;
    const float* eps = rel ? ipq : up;
    const float* kfq = rel ? ikf : ukf;
    const float* kps = rel ? ikp : ukp;
    float* agg = rel ? agg_i : agg_u;
    float* den = rel ? den_i : den_u;

    int lane = threadIdx.x & 15;
    int grp  = threadIdx.x >> 4;
    int base = rblk * 256 + grp * 16;
    if (base >= E) return;
    float ef0 = efq[lane], ef1 = efq[lane + 16], ef2 = efq[lane + 32], ef3 = efq[lane + 48];
    float ep0 = eps[lane], ep1 = eps[lane + 16], ep2 = eps[lane + 32], ep3 = eps[lane + 48];
    float kf0 = kfq[lane], kf1 = kfq[lane + 16], kf2 = kfq[lane + 32], kf3 = kfq[lane + 48];
    float kp0 = kps[lane], kp1 = kps[lane + 16], kp2 = kps[lane + 32], kp3 = kps[lane + 48];
    bool same = ef0 == kf0 && ef1 == kf1 && ef2 == kf2 && ef3 == kf3 &&
                ep0 == kp0 && ep1 == kp1 && ep2 == kp2 && ep3 == kp3;
    same = __all(same);  // uniform: key time-encode identical to e time-encode

    float a0 = 0, a1 = 0, a2 = 0, a3 = 0, dn = 0;
    float d0 = 0, d1 = 0, d2 = 0, d3 = 0;
    int cur = -1;
    for (int j = 0; j < 16; ++j) {
        int e = base + j;
        if (e >= E) break;
        int2 st = est[e];
        int s = st.x; float t = __int_as_float(st.y);
        int dd = ed[e];
        if (dd != cur) {  // group-uniform
            if (cur >= 0) {
                float* ap = &agg[(size_t)cur * D + lane];
                unsafeAtomicAdd(ap +  0, a0); unsafeAtomicAdd(ap + 16, a1);
                unsafeAtomicAdd(ap + 32, a2); unsafeAtomicAdd(ap + 48, a3);
                if (lane == 0) unsafeAtomicAdd(&den[cur], dn);
            }
            a0 = a1 = a2 = a3 = 0; dn = 0; cur = dd;
            const unsigned short* dp = &dstF[(size_t)dd * D + lane];
            d0 = bf2f(dp[0]); d1 = bf2f(dp[16]); d2 = bf2f(dp[32]); d3 = bf2f(dp[48]);
        }
        const unsigned short* sp = &srcF[(size_t)s * D + lane];
        float s0 = bf2f(sp[0]), s1 = bf2f(sp[16]), s2 = bf2f(sp[32]), s3 = bf2f(sp[48]);
        float c0 = __cosf(fmaf(t, ef0, ep0));
        float c1 = __cosf(fmaf(t, ef1, ep1));
        float c2 = __cosf(fmaf(t, ef2, ep2));
        float c3 = __cosf(fmaf(t, ef3, ep3));
        float p = (c0 + s0) * d0 + (c1 + s1) * d1 + (c2 + s2) * d2 + (c3 + s3) * d3;
        p += __shfl_xor(p, 1); p += __shfl_xor(p, 2);
        p += __shfl_xor(p, 4); p += __shfl_xor(p, 8);
        float ex = __expf(p * 0.125f);
        float k0, k1, k2, k3;
        if (same) { k0 = c0; k1 = c1; k2 = c2; k3 = c3; }
        else {
            k0 = __cosf(fmaf(t, kf0, kp0)); k1 = __cosf(fmaf(t, kf1, kp1));
            k2 = __cosf(fmaf(t, kf2, kp2)); k3 = __cosf(fmaf(t, kf3, kp3));
        }
        a0 = fmaf(ex, s0 + k0, a0); a1 = fmaf(ex, s1 + k1, a1);
        a2 = fmaf(ex, s2 + k2, a2); a3 = fmaf(ex, s3 + k3, a3);
        dn += ex;
    }
    if (cur >= 0) {
        float* ap = &agg[(size_t)cur * D + lane];
        unsafeAtomicAdd(ap +  0, a0); unsafeAtomicAdd(ap + 16, a1);
        unsafeAtomicAdd(ap + 32, a2); unsafeAtomicAdd(ap + 48, a3);
        if (lane == 0) unsafeAtomicAdd(&den[cur], dn);
    }
}

// ============================ update: W2-in-VGPR (128), broadcast-row, ELU =======================
__global__ __launch_bounds__(256) void k_update3(
    float* __restrict__ user_h, float* __restrict__ item_h,
    const float* __restrict__ agg_u, const float* __restrict__ den_u,
    const float* __restrict__ agg_i, const float* __restrict__ den_i,
    const float* __restrict__ Wuu_l, const float* __restrict__ Wii_l,
    int NU, int NI, int G) {
    bool rel = blockIdx.x >= (unsigned)G;
    int b = rel ? blockIdx.x - G : blockIdx.x;
    float* h = rel ? item_h : user_h;
    const float* agg = rel ? agg_i : agg_u;
    const float* den = rel ? den_i : den_u;
    const float* W2  = rel ? Wii_l : Wuu_l;
    int n = rel ? NI : NU;
    int lane = threadIdx.x & 63;
    int gw = b * 4 + (threadIdx.x >> 6);
    int nw = G * 4;
    float w[2 * D];
#pragma unroll
    for (int d = 0; d < 2 * D; ++d) w[d] = W2[d * D + lane];
    for (int row = gw; row < n; row += nw) {
        const float4* ar = (const float4*)&agg[(size_t)row * D];
        const float4* hr = (const float4*)&h[(size_t)row * D];
        float dd = den[row];
        float inv = dd > 0.f ? 1.f / dd : 0.f;   // empty segment -> agg contribution 0
        float acca = 0.f, acch = 0.f;
#pragma unroll
        for (int c = 0; c < 16; ++c) {
            float4 v = ar[c];                    // broadcast
            acca = fmaf(v.x, w[4 * c + 0], acca);
            acca = fmaf(v.y, w[4 * c + 1], acca);
            acca = fmaf(v.z, w[4 * c + 2], acca);
            acca = fmaf(v.w, w[4 * c + 3], acca);
        }
#pragma unroll
        for (int c = 0; c < 16; ++c) {
            float4 v = hr[c];                    // broadcast
            acch = fmaf(v.x, w[D + 4 * c + 0], acch);
            acch = fmaf(v.y, w[D + 4 * c + 1], acch);
            acch = fmaf(v.z, w[D + 4 * c + 2], acch);
            acch = fmaf(v.w, w[D + 4 * c + 3], acch);
        }
        float o = acca * inv + acch;
        h[(size_t)row * D + lane] = o > 0.f ? o : __expf(o) - 1.f;  // elu
    }
}

// ============================ tail ============================
__global__ __launch_bounds__(256) void k_gather_feat(const float* __restrict__ h,
                                                     const int* __restrict__ idx,
                                                     float* __restrict__ feat, int B,
                                                     int colOff, int FW) {
    int i = blockIdx.x * blockDim.x + threadIdx.x;
    if (i >= B * D) return;
    int b = i >> 6, c = i & 63;
    feat[(size_t)b * FW + colOff + c] = h[(size_t)idx[b] * D + c];
}

__global__ __launch_bounds__(64) void k_final(const float* __restrict__ feat,
                                              const float* __restrict__ uW,
                                              const float* __restrict__ dW,
                                              const float* __restrict__ db,
                                              float* __restrict__ out, int B, int FW) {
    __shared__ float fr[512];
    __shared__ float un[D];
    int b = blockIdx.x;
    int c = threadIdx.x;
    for (int i = c; i < FW; i += 64) fr[i] = feat[(size_t)b * FW + i];
    __syncthreads();
    float acc = 0.f;
    for (int d = 0; d < FW; ++d) acc += fr[d] * uW[d * D + c];
    un[c] = acc;
    __syncthreads();
    if (c < 3) {
        float o = db[c];
#pragma unroll
        for (int d = 0; d < D; ++d) o += un[d] * dW[d * 3 + c];
        out[b * 3 + c] = o > 0.f ? o : 0.f;
    }
}

// ============================ launch ============================
extern "C" void kernel_launch(void* const* d_in, const int* in_sizes, int n_in,
                              void* d_out, int out_size, void* d_ws, size_t ws_size,
                              hipStream_t stream) {
    const float* user_emb = (const float*)d_in[0];
    const float* item_emb = (const float*)d_in[1];
    const float* Wu       = (const float*)d_in[2];
    const float* Wi       = (const float*)d_in[3];
    const float* Wuu      = (const float*)d_in[4];
    const float* Wii      = (const float*)d_in[5];
    const float* u_freq   = (const float*)d_in[6];
    const float* u_phase  = (const float*)d_in[7];
    const float* uk_freq  = (const float*)d_in[8];
    const float* uk_phase = (const float*)d_in[9];
    const float* i_freq   = (const float*)d_in[10];
    const float* i_phase  = (const float*)d_in[11];
    const float* ik_freq  = (const float*)d_in[12];
    const float* ik_phase = (const float*)d_in[13];
    const float* unified_W = (const float*)d_in[14];
    const float* dense_W   = (const float*)d_in[15];
    const float* dense_b   = (const float*)d_in[16];
    const float* by_time   = (const float*)d_in[17];
    const float* pby_time  = (const float*)d_in[18];
    const int* user_id   = (const int*)d_in[19];
    const int* item_id   = (const int*)d_in[20];
    const int* by_src    = (const int*)d_in[21];
    const int* by_dst    = (const int*)d_in[22];
    const int* pby_src   = (const int*)d_in[23];
    const int* pby_dst   = (const int*)d_in[24];
    const int* user_index = (const int*)d_in[25];
    const int* last_item_index = (const int*)d_in[26];

    const int NU = in_sizes[19];
    const int NI = in_sizes[20];
    const int E  = in_sizes[21];
    const int B  = in_sizes[25];
    const int L  = in_sizes[2] / (D * D);
    const int FW = (L + 1) * D;

    // ---- workspace: [agg_u|agg_i|den_u|den_i] zeroed per layer; [cur_u|cur_i] zeroed once ----
    char* wp = (char*)d_ws;
    auto alloc_f = [&](size_t n) { float* p = (float*)wp; wp += n * sizeof(float); return p; };
    auto alloc_i = [&](size_t n) { int* p = (int*)wp; wp += n * sizeof(int); return p; };
    auto alloc_i2 = [&](size_t n) { int2* p = (int2*)wp; wp += n * sizeof(int2); return p; };
    auto alloc_h = [&](size_t n) { unsigned short* p = (unsigned short*)wp; wp += n * sizeof(unsigned short); return p; };
    float* agg_u = alloc_f((size_t)NU * D);
    float* agg_i = alloc_f((size_t)NI * D);
    float* den_u = alloc_f(NU);
    float* den_i = alloc_f(NI);
    size_t zero_bytes = (size_t)(wp - (char*)d_ws);
    int2* by_st  = alloc_i2(E);     // 8B-aligned (all prior sizes are multiples of 8)
    int2* pby_st = alloc_i2(E);
    int* cur_u = alloc_i(NU);
    int* cur_i = alloc_i(NI);
    size_t cur_bytes = (size_t)NU * 4 + (size_t)NI * 4;
    float* user_h = alloc_f((size_t)NU * D);
    float* item_h = alloc_f((size_t)NI * D);
    unsigned short* uh = alloc_h((size_t)NU * D);
    unsigned short* ih = alloc_h((size_t)NI * D);
    int*   by_dsts    = alloc_i(E);
    int*   pby_dsts   = alloc_i(E);
    int*   by_rowptr  = alloc_i(NU + 2);
    int*   pby_rowptr = alloc_i(NI + 2);
    int*   bsums      = alloc_i(512);
    float* feat       = alloc_f((size_t)B * FW);

    const int nbU = (NU + 2047) / 2048, nbI = (NI + 2047) / 2048;

    // initial node features
    k_gather2<<<((NU + NI) * D + 255) / 256, 256, 0, stream>>>(
        user_emb, item_emb, user_id, item_id, user_h, item_h, NU, NI);

    // dst-sorted edge lists, both relations
    hipMemsetAsync(cur_u, 0, cur_bytes, stream);
    k_hist2<<<2048, 256, 0, stream>>>(by_dst, pby_dst, cur_u, cur_i, E);
    k_scan_block2<<<nbU + nbI, 256, 0, stream>>>(cur_u, by_rowptr, cur_i, pby_rowptr,
                                                 bsums, nbU, NU, NI);
    k_scan_small<<<1, 256, 0, stream>>>(bsums, nbU, nbI);
    k_fixup2<<<(NU + NI + 255) / 256, 256, 0, stream>>>(by_rowptr, pby_rowptr, bsums,
                                                        cur_u, cur_i, NU, NI, E, nbU);
    k_scatter2<<<2048, 256, 0, stream>>>(by_src, by_dst, by_time,
                                         pby_src, pby_dst, pby_time,
                                         cur_u, cur_i,
                                         by_st, by_dsts,
                                         pby_st, pby_dsts, E);

    const int EB = (E + 255) / 256;
    const int G = 256;  // blocks per table for transform/update (grid-stride waves)
    for (int l = 0; l < L; ++l) {
        hipMemsetAsync(d_ws, 0, zero_bytes, stream);
        k_transform3<<<2 * G, 256, 0, stream>>>(user_h, item_h,
                                                Wu + l * D * D, Wi + l * D * D,
                                                uh, ih, NU, NI, G);
        k_edge2<<<2 * EB, 256, 0, stream>>>(
            ih, uh,
            by_st, by_dsts,
            pby_st, pby_dsts,
            u_freq + l * D, u_phase + l * D, uk_freq + l * D, uk_phase + l * D,
            i_freq + l * D, i_phase + l * D, ik_freq + l * D, ik_phase + l * D,
            agg_u, den_u, agg_i, den_i, E, EB);
        k_update3<<<2 * G, 256, 0, stream>>>(user_h, item_h,
                                             agg_u, den_u, agg_i, den_i,
                                             Wuu + (size_t)l * 2 * D * D,
                                             Wii + (size_t)l * 2 * D * D,
                                             NU, NI, G);
        k_gather_feat<<<(B * D + 255) / 256, 256, 0, stream>>>(user_h, user_index, feat, B,
                                                               l * D, FW);
    }
    k_gather_feat<<<(B * D + 255) / 256, 256, 0, stream>>>(item_h, last_item_index, feat, B,
                                                           L * D, FW);
    k_final<<<B, 64, 0, stream>>>(feat, unified_W, dense_W, dense_b, (float*)d_out, B, FW);
}